// Round 4
// baseline (2654.093 us; speedup 1.0000x reference)
//
#include <hip/hip_runtime.h>
#include <hip/hip_bf16.h>

#define B_ 16
#define S_ 512
#define H_ 512
#define V_ 10000
#define G_ 2048
#define M_ (B_*S_)   // 8192 tokens

typedef short bf16x8 __attribute__((ext_vector_type(8)));
typedef float f32x4 __attribute__((ext_vector_type(4)));
typedef _Float16 f16x8 __attribute__((ext_vector_type(8)));
typedef unsigned int u32x4 __attribute__((ext_vector_type(4)));

static __device__ __forceinline__ unsigned short f2bf(float x) {
    union { float f; unsigned int u; } v; v.f = x;
    unsigned int r = v.u + 0x7fffu + ((v.u >> 16) & 1u);   // RNE
    return (unsigned short)(r >> 16);
}
static __device__ __forceinline__ unsigned short f2h_bits(float x) {
    _Float16 h = (_Float16)x;
    return __builtin_bit_cast(unsigned short, h);
}
static __device__ __forceinline__ float ftanh(float x) {
    float ax = fabsf(x);
    float e  = __expf(-2.f*ax);
    float r  = (1.f - e) / (1.f + e);
    return copysignf(r, x);
}

// 64B batched load through the XCD-local L2 (sc0 = bypass L1, served by L2).
static __device__ __forceinline__ void ld64_sc0(const void* p, u32x4& a, u32x4& b, u32x4& c, u32x4& d) {
    asm volatile("global_load_dwordx4 %0, %4, off sc0\n\t"
                 "global_load_dwordx4 %1, %4, off offset:16 sc0\n\t"
                 "global_load_dwordx4 %2, %4, off offset:32 sc0\n\t"
                 "global_load_dwordx4 %3, %4, off offset:48 sc0\n\t"
                 "s_waitcnt vmcnt(0)"
                 : "=&v"(a), "=&v"(b), "=&v"(c), "=&v"(d)
                 : "v"(p) : "memory");
}
static __device__ __forceinline__ void st_sc0(void* p, unsigned long long v) {
    asm volatile("global_store_dwordx2 %0, %1, off sc0" :: "v"(p), "v"(v) : "memory");
}

// ---------------------------------------------------------------------------
// prep:
//  - w_ih0 -> bf16 row-major (GEMM B operand)
//  - w_hh0 -> f16 MFMA B-frags, 16-block layout [j16][kc16][wrow8][lane64][e8]
//      r = wrow*16+(l&15); R = (r>>5)*512 + j*32 + (r&31); k = kc*32+(l>>4)*8+e
//  - w_ih1, w_hh1 -> f16 MFMA B-frags, 32-block layout [j32][kc16][nt4][lane64][e8]
//      R = nt*512 + j*16 + (l&15); k = kc*32+(l>>4)*8+e   (nt = gate)
//  - w1,w2 -> bf16; biases combined; bump launch counter; zero l1prog
// ---------------------------------------------------------------------------
__global__ void prep_kernel(const float* __restrict__ w_ih0, const float* __restrict__ w_hh0,
                            const float* __restrict__ b_ih0, const float* __restrict__ b_hh0,
                            const float* __restrict__ w_ih1, const float* __restrict__ w_hh1,
                            const float* __restrict__ b_ih1, const float* __restrict__ b_hh1,
                            const float* __restrict__ w1,   const float* __restrict__ w2,
                            unsigned short* __restrict__ w_ih0_b, _Float16* __restrict__ wfrag0,
                            _Float16* __restrict__ wfrag1x,      _Float16* __restrict__ wfrag1h,
                            unsigned short* __restrict__ w1_b,    unsigned short* __restrict__ w2_b,
                            float* __restrict__ bias0, float* __restrict__ bias1,
                            unsigned int* __restrict__ l1prog, unsigned int* __restrict__ lc_slot) {
    if (blockIdx.x == 0 && threadIdx.x == 0) atomicAdd(lc_slot, 1u);
    if (blockIdx.x == 0 && threadIdx.x < 64) l1prog[threadIdx.x*16] = 0u;
    int i  = blockIdx.x * blockDim.x + threadIdx.x;
    int st = gridDim.x * blockDim.x;
    for (int k = i; k < G_*H_; k += st) w_ih0_b[k] = f2bf(w_ih0[k]);
    // layer-0 recurrent frags (16-block)
    for (int d = i; d < G_*H_; d += st) {
        int e    = d & 7;
        int l    = (d >> 3) & 63;
        int wrow = (d >> 9) & 7;
        int kc   = (d >> 12) & 15;
        int j    = (d >> 16) & 15;
        int r    = wrow*16 + (l & 15);
        int R    = (r >> 5)*512 + j*32 + (r & 31);
        int k    = kc*32 + ((l >> 4) << 3) + e;
        wfrag0[d] = (_Float16)w_hh0[R*H_ + k];
    }
    // layer-1 frags (32-block): x-part (w_ih1) and h-part (w_hh1)
    for (int d = i; d < G_*H_; d += st) {
        int e  = d & 7;
        int l  = (d >> 3) & 63;
        int nt = (d >> 9) & 3;
        int kc = (d >> 11) & 15;
        int j  = (d >> 15) & 31;
        int R  = nt*512 + j*16 + (l & 15);
        int k  = kc*32 + ((l >> 4) << 3) + e;
        wfrag1x[d] = (_Float16)w_ih1[R*H_ + k];
        wfrag1h[d] = (_Float16)w_hh1[R*H_ + k];
    }
    for (int k = i; k < V_*128; k += st) w2_b[k] = f2bf(w2[k]);
    for (int k = i; k < 128*H_; k += st) w1_b[k] = f2bf(w1[k]);
    for (int k = i; k < G_;     k += st) { bias0[k] = b_ih0[k] + b_hh0[k]; bias1[k] = b_ih1[k] + b_hh1[k]; }
}

// ---------------------------------------------------------------------------
__global__ void embed_kernel(const int* __restrict__ src, const float* __restrict__ w_emb,
                             const float* __restrict__ b_emb, unsigned short* __restrict__ emb) {
    int m = blockIdx.x;
    int idx = src[m];
    for (int h = threadIdx.x; h < H_; h += blockDim.x)
        emb[(long)m*H_ + h] = f2bf(w_emb[(long)h*V_ + idx] + b_emb[h]);
}

// ---------------------------------------------------------------------------
// Generic bf16 MFMA GEMM: C[M,N] = A[M,K] @ B[N,K]^T + bias[N]
// ---------------------------------------------------------------------------
template<bool RELU, bool OUT_BF16>
__launch_bounds__(256)
__global__ void gemm_kernel(const unsigned short* __restrict__ A, const unsigned short* __restrict__ Bm,
                            const float* __restrict__ bias, void* __restrict__ Cout,
                            int Ndim, int K) {
    __shared__ unsigned short At[128*40];
    __shared__ unsigned short Bt[128*40];
    int m0 = blockIdx.y * 128;
    int n0 = blockIdx.x * 128;
    int tid  = threadIdx.x;
    int lane = tid & 63, wave = tid >> 6;
    int wm = (wave >> 1) * 64, wn = (wave & 1) * 64;
    int l15 = lane & 15, l4 = lane >> 4;
    f32x4 acc[4][4] = {};

    for (int kk = 0; kk < K; kk += 32) {
        __syncthreads();
        #pragma unroll
        for (int rep = 0; rep < 2; ++rep) {
            int gid = tid + rep*256;
            int row = gid >> 2, c8 = (gid & 3) << 3;
            *(uint4*)&At[row*40 + c8] = *(const uint4*)&A[(long)(m0+row)*K + kk + c8];
            int nrow = n0 + row; if (nrow >= Ndim) nrow = Ndim - 1;
            *(uint4*)&Bt[row*40 + c8] = *(const uint4*)&Bm[(long)nrow*K + kk + c8];
        }
        __syncthreads();
        bf16x8 af[4], bfr[4];
        #pragma unroll
        for (int i = 0; i < 4; ++i)
            af[i] = *(const bf16x8*)&At[(wm + i*16 + l15)*40 + l4*8];
        #pragma unroll
        for (int j = 0; j < 4; ++j)
            bfr[j] = *(const bf16x8*)&Bt[(wn + j*16 + l15)*40 + l4*8];
        #pragma unroll
        for (int i = 0; i < 4; ++i)
            #pragma unroll
            for (int j = 0; j < 4; ++j)
                acc[i][j] = __builtin_amdgcn_mfma_f32_16x16x32_bf16(af[i], bfr[j], acc[i][j], 0, 0, 0);
    }

    #pragma unroll
    for (int i = 0; i < 4; ++i) {
        int row = m0 + wm + i*16 + l4*4;
        #pragma unroll
        for (int j = 0; j < 4; ++j) {
            int col = n0 + wn + j*16 + l15;
            if (col < Ndim) {
                float bv = bias[col];
                #pragma unroll
                for (int r = 0; r < 4; ++r) {
                    float v = acc[i][j][r] + bv;
                    if (RELU) v = v > 0.f ? v : 0.f;
                    if (OUT_BF16) ((unsigned short*)Cout)[(long)(row+r)*Ndim + col] = f2bf(v);
                    else          ((float*)Cout)[(long)(row+r)*Ndim + col] = v;
                }
            }
        }
    }
}

// ---------------------------------------------------------------------------
// Fused 2-layer wavefront-pipelined LSTM, XCD-local exchange.
//  Grid = 256 blocks (96KB LDS forces 1/CU => all co-resident, every CU).
//  Role: bid%8==0, bid/8<16  -> layer 0, j  = bid/8 (16 blocks, one XCD under
//        round-robin dispatch); bid%8==1, bid/8<32 -> layer 1, j1 = bid/8
//        (32 blocks, another XCD); everyone else exits.
//  Weights live in REGISTERS (16 f16x8 frags per wave) - no weight LDS.
//  Exchange: tagged u64 slots (hi32=(lc<<16)|(t+1)). Producers DUAL-publish:
//   - agent master (h0ex/h1ex, rotating 16/4 slabs) - always correct
//   - sc0 mirror (h0mir/h1mir) - coherent only within the producer's XCD
//  Consumers: bounded sc0-local spin -> fallback to agent master. If the
//  fallback's FIRST round already sees the tag (=> local view is blind, i.e.
//  blocks not co-resident on an XCD), after 4 hits the local path is disabled.
//  Cross-layer h0->L1 stays agent-scope (speculatively issued early so its
//  RTT overlaps the h1-local wait). Backpressure L1->L0 via l1prog as before.
// ---------------------------------------------------------------------------
__launch_bounds__(512)
__global__ void lstm_fused_kernel(const float* __restrict__ xp,
                                  const _Float16* __restrict__ wfrag0,
                                  const _Float16* __restrict__ wfrag1x,
                                  const _Float16* __restrict__ wfrag1h,
                                  const float* __restrict__ bias1,
                                  unsigned long long* __restrict__ h0ex,
                                  unsigned long long* __restrict__ h1ex,
                                  unsigned long long* __restrict__ h0mir,
                                  unsigned long long* __restrict__ h1mir,
                                  unsigned int* __restrict__ l1prog,
                                  const unsigned int* __restrict__ lc_slot,
                                  unsigned short* __restrict__ hout) {
    __shared__ __align__(16) char smem[98304];   // big on purpose: 1 block/CU
    int bid = blockIdx.x;
    int mod = bid & 7, grp = bid >> 3;
    bool isL0 = (mod == 0) && (grp < 16);
    bool isL1 = (mod == 1) && (grp < 32);
    if (!isL0 && !isL1) return;

    int tid  = threadIdx.x;
    int lane = tid & 63, wave = tid >> 6;
    int l15  = lane & 15, l4 = lane >> 4;
    unsigned int base = __hip_atomic_load(lc_slot, __ATOMIC_RELAXED, __HIP_MEMORY_SCOPE_AGENT) << 16;

    if (isL0) {
        // ================= layer 0 =================
        _Float16* h_lds = (_Float16*)smem;              // [16][520]
        float*    gbuf  = (float*)(smem + 16640);       // [16][132]
        int j = grp;
        // recurrent weight fragments -> registers (loop-invariant)
        const f16x8* w0g = (const f16x8*)wfrag0 + (long)j*8192;
        f16x8 bfr[16];
        #pragma unroll
        for (int kc = 0; kc < 16; ++kc) bfr[kc] = w0g[(kc*8 + wave)*64 + lane];
        for (int i2 = tid; i2 < 4160; i2 += 512) ((unsigned int*)h_lds)[i2] = 0;
        __syncthreads();
        int ch = tid >> 5, s = tid & 31;
        float c = 0.f;
        bool useLocal = true; int miss = 0;

        for (int t = 0; t < S_; ++t) {
            const float* xr = xp + ((long)ch*S_ + t)*G_ + j*32 + s;
            float xi = xr[0], xf = xr[512], xg = xr[1024], xo = xr[1536];
            // backpressure: before overwriting slab (t&15), ensure all 32
            // layer-1 blocks consumed h0 through step t-8.
            if (wave == 0 && t >= 16 && (t & 7) == 0) {
                unsigned int thr = base + (unsigned int)(t - 8);
                unsigned int pv = __hip_atomic_load(l1prog + (lane & 31)*16, __ATOMIC_RELAXED, __HIP_MEMORY_SCOPE_AGENT);
                while (!__all((int)(pv >= thr))) {
                    __builtin_amdgcn_s_sleep(4);
                    pv = __hip_atomic_load(l1prog + (lane & 31)*16, __ATOMIC_RELAXED, __HIP_MEMORY_SCOPE_AGENT);
                }
            }
            if (t > 0) {
                unsigned int tagv = base + (unsigned int)t;
                long slab = (long)((t-1) & 15) * 4096;
                u32x4 pa, pb, pc, pd;
                bool got = false;
                if (useLocal) {
                    const unsigned long long* mb = h0mir + slab + (long)tid*8;
                    for (int r = 0; r < 16; ++r) {
                        ld64_sc0(mb, pa, pb, pc, pd);
                        if (pa.y==tagv && pa.w==tagv && pb.y==tagv && pb.w==tagv &&
                            pc.y==tagv && pc.w==tagv && pd.y==tagv && pd.w==tagv) { got = true; break; }
                        __builtin_amdgcn_s_sleep(1);
                    }
                }
                if (!got) {
                    const unsigned long long* gb8 = h0ex + slab + (long)tid*8;
                    unsigned long long v[8];
                    int ar = 0;
                    for (;;) {
                        #pragma unroll
                        for (int q = 0; q < 8; ++q)
                            v[q] = __hip_atomic_load(gb8 + q, __ATOMIC_RELAXED, __HIP_MEMORY_SCOPE_AGENT);
                        bool ok = true;
                        #pragma unroll
                        for (int q = 0; q < 8; ++q) ok &= ((unsigned int)(v[q] >> 32) == tagv);
                        if (ok) break;
                        ++ar;
                        __builtin_amdgcn_s_sleep(1);
                    }
                    if (useLocal && ar == 0 && ++miss >= 4) useLocal = false;
                    pa.x=(unsigned int)v[0]; pa.z=(unsigned int)v[1];
                    pb.x=(unsigned int)v[2]; pb.z=(unsigned int)v[3];
                    pc.x=(unsigned int)v[4]; pc.z=(unsigned int)v[5];
                    pd.x=(unsigned int)v[6]; pd.z=(unsigned int)v[7];
                }
                // thread covers chain tid>>5, cols (tid&31)*16 .. +16
                unsigned int* hl = (unsigned int*)&h_lds[ch*520 + s*16];
                hl[0]=pa.x; hl[1]=pa.z; hl[2]=pb.x; hl[3]=pb.z;
                hl[4]=pc.x; hl[5]=pc.z; hl[6]=pd.x; hl[7]=pd.z;
            }
            __syncthreads();
            f32x4 acc = {0.f,0.f,0.f,0.f};
            #pragma unroll
            for (int kc = 0; kc < 16; ++kc) {
                f16x8 af = *(const f16x8*)&h_lds[l15*520 + kc*32 + l4*8];
                acc = __builtin_amdgcn_mfma_f32_16x16x32_f16(af, bfr[kc], acc, 0, 0, 0);
            }
            #pragma unroll
            for (int r = 0; r < 4; ++r)
                gbuf[(l4*4 + r)*132 + wave*16 + l15] = acc[r];
            __syncthreads();
            const float* gb = gbuf + ch*132;
            xi += gb[s]; xf += gb[32+s]; xg += gb[64+s]; xo += gb[96+s];
            float ig = 1.f/(1.f+__expf(-xi));
            float fg = 1.f/(1.f+__expf(-xf));
            float gg = ftanh(xg);
            float og = 1.f/(1.f+__expf(-xo));
            c = fg*c + ig*gg;
            float h = og*ftanh(c);
            unsigned int me = f2h_bits(h);
            unsigned int up = (unsigned int)__shfl_down((int)me, 1, 64);
            if (!(s & 1)) {
                unsigned long long vv = ((unsigned long long)(base + (unsigned int)(t+1)) << 32)
                                      | (up << 16) | me;
                long slot = (long)(t & 15)*4096 + ch*256 + j*16 + (s>>1);
                __hip_atomic_store(&h0ex[slot], vv, __ATOMIC_RELAXED, __HIP_MEMORY_SCOPE_AGENT);
                st_sc0((void*)&h0mir[slot], vv);
            }
        }
    } else {
        // ================= layer 1 =================
        _Float16* h0l  = (_Float16*)smem;               // [16][520]
        _Float16* h1l  = h0l + 16*520;                  // [16][520]
        float*    gbuf = (float*)(smem + 33280);        // [2][4][16][17]
        float*    bl   = (float*)(smem + 33280 + 8704); // [64]
        int j1 = grp;
        int ntw = wave & 3, srcw = wave >> 2;
        const f16x8* wsrc = ((const f16x8*)(srcw ? wfrag1h : wfrag1x)) + (long)j1*4096;
        f16x8 bfr[16];
        #pragma unroll
        for (int kc = 0; kc < 16; ++kc) bfr[kc] = wsrc[(kc*4 + ntw)*64 + lane];
        if (tid < 64) bl[tid] = bias1[(tid >> 4)*512 + j1*16 + (tid & 15)];
        for (int i2 = tid; i2 < 8320; i2 += 512) ((unsigned int*)h0l)[i2] = 0;  // zero h0l+h1l
        __syncthreads();
        int ch = tid >> 4, sc = tid & 15;
        float c = 0.f;
        bool useLocal = true; int miss = 0;

        for (int t = 0; t < S_; ++t) {
            unsigned int tag0 = base + (unsigned int)(t+1);
            unsigned int tag1 = base + (unsigned int)t;
            // speculative early issue of the (cross-XCD) h0 loads
            const unsigned long long* b0 = h0ex + (long)(t & 15)*4096;
            unsigned long long v0[8];
            #pragma unroll
            for (int q = 0; q < 8; ++q)
                v0[q] = __hip_atomic_load(b0 + q*512 + tid, __ATOMIC_RELAXED, __HIP_MEMORY_SCOPE_AGENT);
            // h1(t-1): local mirror spin -> agent fallback
            if (t > 0) {
                long slab1 = (long)((t-1) & 3)*4096;
                u32x4 pa, pb, pc, pd;
                bool got = false;
                if (useLocal) {
                    const unsigned long long* mb = h1mir + slab1 + (long)tid*8;
                    for (int r = 0; r < 16; ++r) {
                        ld64_sc0(mb, pa, pb, pc, pd);
                        if (pa.y==tag1 && pa.w==tag1 && pb.y==tag1 && pb.w==tag1 &&
                            pc.y==tag1 && pc.w==tag1 && pd.y==tag1 && pd.w==tag1) { got = true; break; }
                        __builtin_amdgcn_s_sleep(1);
                    }
                }
                if (!got) {
                    const unsigned long long* gb8 = h1ex + slab1 + (long)tid*8;
                    unsigned long long v[8];
                    int ar = 0;
                    for (;;) {
                        #pragma unroll
                        for (int q = 0; q < 8; ++q)
                            v[q] = __hip_atomic_load(gb8 + q, __ATOMIC_RELAXED, __HIP_MEMORY_SCOPE_AGENT);
                        bool ok = true;
                        #pragma unroll
                        for (int q = 0; q < 8; ++q) ok &= ((unsigned int)(v[q] >> 32) == tag1);
                        if (ok) break;
                        ++ar;
                        __builtin_amdgcn_s_sleep(1);
                    }
                    if (useLocal && ar == 0 && ++miss >= 4) useLocal = false;
                    pa.x=(unsigned int)v[0]; pa.z=(unsigned int)v[1];
                    pb.x=(unsigned int)v[2]; pb.z=(unsigned int)v[3];
                    pc.x=(unsigned int)v[4]; pc.z=(unsigned int)v[5];
                    pd.x=(unsigned int)v[6]; pd.z=(unsigned int)v[7];
                }
                unsigned int* hl = (unsigned int*)&h1l[(tid >> 5)*520 + (tid & 31)*16];
                hl[0]=pa.x; hl[1]=pa.z; hl[2]=pb.x; hl[3]=pb.z;
                hl[4]=pc.x; hl[5]=pc.z; hl[6]=pd.x; hl[7]=pd.z;
            }
            // resolve h0(t) (agent; usually already landed)
            {
                bool ok0 = true;
                #pragma unroll
                for (int q = 0; q < 8; ++q) ok0 &= ((unsigned int)(v0[q] >> 32) == tag0);
                if (!ok0) {
                    for (;;) {
                        #pragma unroll
                        for (int q = 0; q < 8; ++q)
                            v0[q] = __hip_atomic_load(b0 + q*512 + tid, __ATOMIC_RELAXED, __HIP_MEMORY_SCOPE_AGENT);
                        bool ok = true;
                        #pragma unroll
                        for (int q = 0; q < 8; ++q) ok &= ((unsigned int)(v0[q] >> 32) == tag0);
                        if (ok) break;
                        __builtin_amdgcn_s_sleep(1);
                    }
                }
                #pragma unroll
                for (int q = 0; q < 8; ++q) {
                    int w = q*512 + tid;
                    *(unsigned int*)&h0l[(w >> 8)*520 + (w & 255)*2] = (unsigned int)v0[q];
                }
            }
            __syncthreads();
            if (tid == 0)
                __hip_atomic_store(l1prog + j1*16, base + (unsigned int)t,
                                   __ATOMIC_RELAXED, __HIP_MEMORY_SCOPE_AGENT);
            // MFMA: wave -> (src = wave>>2, gate nt = wave&3); 16 chained each
            {
                const _Float16* hs = srcw ? h1l : h0l;
                f32x4 acc = {0.f,0.f,0.f,0.f};
                #pragma unroll
                for (int kc = 0; kc < 16; ++kc) {
                    f16x8 af = *(const f16x8*)&hs[l15*520 + kc*32 + l4*8];
                    acc = __builtin_amdgcn_mfma_f32_16x16x32_f16(af, bfr[kc], acc, 0, 0, 0);
                }
                #pragma unroll
                for (int r = 0; r < 4; ++r)
                    gbuf[(wave*16 + l4*4 + r)*17 + l15] = acc[r];
            }
            __syncthreads();
            if (tid < 256) {
                float xi = gbuf[((0*4+0)*16+ch)*17+sc] + gbuf[((1*4+0)*16+ch)*17+sc] + bl[sc];
                float xf = gbuf[((0*4+1)*16+ch)*17+sc] + gbuf[((1*4+1)*16+ch)*17+sc] + bl[16+sc];
                float xg = gbuf[((0*4+2)*16+ch)*17+sc] + gbuf[((1*4+2)*16+ch)*17+sc] + bl[32+sc];
                float xo = gbuf[((0*4+3)*16+ch)*17+sc] + gbuf[((1*4+3)*16+ch)*17+sc] + bl[48+sc];
                float ig = 1.f/(1.f+__expf(-xi));
                float fg = 1.f/(1.f+__expf(-xf));
                float gg = ftanh(xg);
                float og = 1.f/(1.f+__expf(-xo));
                c = fg*c + ig*gg;
                float h = og*ftanh(c);
                hout[((long)ch*S_ + t)*H_ + j1*16 + sc] = f2bf(h);
                unsigned int me = f2h_bits(h);
                unsigned int up = (unsigned int)__shfl_down((int)me, 1, 64);
                if (!(sc & 1)) {
                    unsigned long long vv = ((unsigned long long)(base + (unsigned int)(t+1)) << 32)
                                          | (up << 16) | me;
                    long slot = (long)(t & 3)*4096 + ch*256 + j1*8 + (sc>>1);
                    __hip_atomic_store(&h1ex[slot], vv, __ATOMIC_RELAXED, __HIP_MEMORY_SCOPE_AGENT);
                    st_sc0((void*)&h1mir[slot], vv);
                }
            }
        }
    }
}

// ---------------------------------------------------------------------------
extern "C" void kernel_launch(void* const* d_in, const int* in_sizes, int n_in,
                              void* d_out, int out_size, void* d_ws, size_t ws_size,
                              hipStream_t stream) {
    const int*   src   = (const int*)  d_in[0];
    const float* w_emb = (const float*)d_in[1];
    const float* b_emb = (const float*)d_in[2];
    const float* w_ih0 = (const float*)d_in[3];
    const float* w_hh0 = (const float*)d_in[4];
    const float* b_ih0 = (const float*)d_in[5];
    const float* b_hh0 = (const float*)d_in[6];
    const float* w_ih1 = (const float*)d_in[7];
    const float* w_hh1 = (const float*)d_in[8];
    const float* b_ih1 = (const float*)d_in[9];
    const float* b_hh1 = (const float*)d_in[10];
    const float* w1    = (const float*)d_in[11];
    const float* b1    = (const float*)d_in[12];
    const float* w2    = (const float*)d_in[13];
    const float* b2    = (const float*)d_in[14];
    float* out = (float*)d_out;

    char* ws = (char*)d_ws;
    size_t off = 0;
    auto alloc = [&](size_t bytes) -> void* {
        void* p = ws + off;
        off = (off + bytes + 255) & ~(size_t)255;
        return p;
    };
    unsigned short* w_ih0_b = (unsigned short*)alloc((size_t)G_*H_*2);
    _Float16*       wfrag0  = (_Float16*)      alloc((size_t)G_*H_*2);
    _Float16*       wfrag1x = (_Float16*)      alloc((size_t)G_*H_*2);
    _Float16*       wfrag1h = (_Float16*)      alloc((size_t)G_*H_*2);
    unsigned short* w1_b    = (unsigned short*)alloc((size_t)128*H_*2);
    unsigned short* w2_b    = (unsigned short*)alloc((size_t)V_*128*2);
    float*          bias0   = (float*)         alloc((size_t)G_*4);
    float*          bias1   = (float*)         alloc((size_t)G_*4);
    unsigned short* emb     = (unsigned short*)alloc((size_t)M_*H_*2);   // reused as hout (h1)
    unsigned short* hidb    = (unsigned short*)alloc((size_t)M_*128*2);
    float*          xp      = (float*)         alloc((size_t)M_*G_*4);
    unsigned long long* h0ex  = (unsigned long long*)alloc((size_t)16*4096*8);  // 512 KB rotating (agent master)
    unsigned long long* h1ex  = (unsigned long long*)alloc((size_t)4*4096*8);   // 128 KB rotating (agent master)
    unsigned long long* h0mir = (unsigned long long*)alloc((size_t)16*4096*8);  // sc0 mirror
    unsigned long long* h1mir = (unsigned long long*)alloc((size_t)4*4096*8);   // sc0 mirror
    unsigned int*   l1prog  = (unsigned int*)  alloc((size_t)64*16*4);
    unsigned int*   lc_slot = (unsigned int*)  alloc((size_t)256);

    prep_kernel<<<2048, 256, 0, stream>>>(w_ih0, w_hh0, b_ih0, b_hh0,
                                          w_ih1, w_hh1, b_ih1, b_hh1,
                                          w1, w2,
                                          w_ih0_b, wfrag0, wfrag1x, wfrag1h,
                                          w1_b, w2_b, bias0, bias1,
                                          l1prog, lc_slot);
    embed_kernel<<<M_, 256, 0, stream>>>(src, w_emb, b_emb, emb);

    // x_proj0 = emb @ w_ih0^T + (b_ih0+b_hh0)   [8192,2048] fp32
    gemm_kernel<false,false><<<dim3(G_/128, M_/128), 256, 0, stream>>>(emb, w_ih0_b, bias0, xp, G_, H_);

    // fused 2-layer pipelined LSTM; h1 (bf16) lands in `emb` buffer (reuse)
    lstm_fused_kernel<<<256, 512, 0, stream>>>(xp, wfrag0, wfrag1x, wfrag1h,
                                               bias1, h0ex, h1ex, h0mir, h1mir,
                                               l1prog, lc_slot, emb);

    // hid = relu(h1 @ w1^T + b1)   [8192,128] bf16
    gemm_kernel<true,true><<<dim3(1, M_/128), 256, 0, stream>>>(emb, w1_b, b1, hidb, 128, H_);

    // logits = hid @ w2^T + b2     [8192,10000] fp32 -> d_out
    gemm_kernel<false,false><<<dim3((V_+127)/128, M_/128), 256, 0, stream>>>(hidb, w2_b, b2, out, V_, 128);
}